// Round 6
// baseline (387.014 us; speedup 1.0000x reference)
//
#include <hip/hip_runtime.h>
#include <hip/hip_bf16.h>
#include <stdint.h>

typedef unsigned long long u64;
typedef unsigned int u32;

#define NANCH 10647
#define NBATCH 16
#define NSORT 16384
#define NSEL 2048
#define NWORD 32
#define CONF_T 0.5f
#define NMS_T 0.5f
#define MAXDET 300
#define MAXWH 4096.0f

// ---------------- Kernel 1: per-anchor prep ----------------
__global__ __launch_bounds__(256) void k_prep(const float* __restrict__ pred,
                                              u64* __restrict__ keys,
                                              float4* __restrict__ boxes,
                                              int* __restrict__ cls,
                                              float* __restrict__ score) {
    __shared__ float sm[128 * 85];
    int b = blockIdx.y;
    int a0 = blockIdx.x * 128;
    int na = NANCH - a0; if (na > 128) na = 128;
    const float* src = pred + ((size_t)b * NANCH + a0) * 85;
    int tot = na * 85;
    for (int i = threadIdx.x; i < tot; i += 256) sm[i] = src[i];
    __syncthreads();
    int t = threadIdx.x;
    if (t < na) {
        const float* s = &sm[t * 85];
        float x = s[0], y = s[1], w = s[2], h = s[3], obj = s[4];
        float best = s[5] * obj; int arg = 0;
        #pragma unroll
        for (int c = 1; c < 80; ++c) {
            float v = s[5 + c] * obj;
            if (v > best) { best = v; arg = c; }
        }
        bool valid = obj >= CONF_T;
        float sc = valid ? best : -1.0f;
        int a = a0 + t;
        float4 bx;
        bx.x = x - w * 0.5f; bx.y = y - h * 0.5f;
        bx.z = x + w * 0.5f; bx.w = y + h * 0.5f;
        size_t o = (size_t)b * NANCH + a;
        boxes[o] = bx;
        cls[o] = arg;
        score[o] = sc;
        u32 u = __float_as_uint(sc);
        u32 v = (u & 0x80000000u) ? ~u : (u | 0x80000000u); // ascending map
        u32 hi = ~v;                                        // descending
        keys[(size_t)b * NSORT + a] = ((u64)hi << 32) | (u32)a;
    }
}

// ------- Kernel 2: radix-select top-2048 + bitonic sort + gather -------
__global__ __launch_bounds__(1024) void k_sel(const u64* __restrict__ keys,
                                              const float4* __restrict__ boxes,
                                              const int* __restrict__ cls,
                                              const float* __restrict__ score,
                                              float4* __restrict__ sel_box,
                                              float4* __restrict__ sel_sbox,
                                              float* __restrict__ sel_area,
                                              float* __restrict__ sel_score,
                                              int* __restrict__ sel_cls) {
    __shared__ u64 sk[NSEL];        // 16 KB
    __shared__ u32 hist[256];
    __shared__ u32 hsc[256];
    __shared__ u64 s_P;             // known-prefix value
    __shared__ u64 s_M;             // known-prefix mask
    __shared__ u32 s_rank;
    __shared__ u32 s_cnt;

    int b = blockIdx.x;
    int tid = threadIdx.x;
    const u64* KB = keys + (size_t)b * NSORT;

    if (tid == 0) { s_P = 0; s_M = 0; s_rank = NSEL; s_cnt = 0; }
    __syncthreads();

    // ---- Phase A: radix-select the 2048th-smallest key ----
    // key bits [31:14] are always zero (index < 16384), so 6 digit rounds
    const int shifts[6] = {56, 48, 40, 32, 8, 0};
    for (int r = 0; r < 6; ++r) {
        int shift = shifts[r];
        if (tid < 256) hist[tid] = 0;
        __syncthreads();
        u64 P = s_P, M = s_M;
        for (int i = tid; i < NANCH; i += 1024) {
            u64 key = KB[i];
            if ((key & M) == P)
                atomicAdd(&hist[(u32)(key >> shift) & 0xFFu], 1u);
        }
        __syncthreads();
        // inclusive scan of hist into hsc (Hillis-Steele over 256)
        if (tid < 256) hsc[tid] = hist[tid];
        __syncthreads();
        for (int d = 1; d < 256; d <<= 1) {
            u32 add = 0;
            if (tid < 256 && tid >= d) add = hsc[tid - d];
            __syncthreads();
            if (tid < 256) hsc[tid] += add;
            __syncthreads();
        }
        // find digit bucket containing current rank
        if (tid < 256) {
            u32 rank = s_rank;
            u32 inc = hsc[tid];
            u32 cb = inc - hist[tid];
            if (cb < rank && rank <= inc) {
                s_rank = rank - cb;
                s_P = s_P | ((u64)tid << shift);
                s_M = s_M | (0xFFull << shift);
            }
        }
        __syncthreads();
    }
    u64 T = s_P;   // the 2048th-smallest key (keys are unique)

    // ---- Phase B: compact the 2048 keys <= T into LDS ----
    for (int i = tid; i < NANCH; i += 1024) {
        u64 key = KB[i];
        if (key <= T) {
            u32 pos = atomicAdd(&s_cnt, 1u);
            sk[pos] = key;
        }
    }
    __syncthreads();

    // ---- Phase C: bitonic sort 2048 keys ascending ----
    for (int k = 2; k <= NSEL; k <<= 1) {
        for (int j = k >> 1; j > 0; j >>= 1) {
            int n = tid;   // exactly NSEL/2 = 1024 compare-exchanges
            int i = ((n & ~(j - 1)) << 1) | (n & (j - 1));
            int l = i | j;
            u64 a = sk[i], c = sk[l];
            bool up = ((i & k) == 0);
            if ((a > c) == up) { sk[i] = c; sk[l] = a; }
            __syncthreads();
        }
    }

    // ---- Phase D: gather selected entries ----
    for (int r = tid; r < NSEL; r += 1024) {
        u64 key = sk[r];
        int a = (int)(key & 0xFFFFFFFFu);
        size_t src = (size_t)b * NANCH + a;
        float4 bx = boxes[src];
        int c = cls[src];
        float sc = score[src];
        float off = (float)c * MAXWH;
        float4 sb;
        sb.x = bx.x + off; sb.y = bx.y + off;
        sb.z = bx.z + off; sb.w = bx.w + off;
        float area = (sb.z - sb.x) * (sb.w - sb.y);
        size_t o = (size_t)b * NSEL + r;
        sel_box[o] = bx; sel_sbox[o] = sb; sel_area[o] = area;
        sel_score[o] = sc; sel_cls[o] = c;
    }
}

// ---------------- Kernel 3: IoU predicate bitmask rows ----------------
__global__ __launch_bounds__(256) void k_iou(const float4* __restrict__ sel_sbox,
                                             const float* __restrict__ sel_area,
                                             u64* __restrict__ rowmask) {
    int b = blockIdx.y;
    int i = blockIdx.x;
    const float4* SB = sel_sbox + (size_t)b * NSEL;
    const float* AR = sel_area + (size_t)b * NSEL;
    float4 bi = SB[i];
    float ai = AR[i];
    int lane = threadIdx.x & 63;
    int wv = threadIdx.x >> 6;
    #pragma unroll
    for (int kk = 0; kk < 8; ++kk) {
        int chunk = wv * 8 + kk;
        int j = chunk * 64 + lane;
        float4 bj = SB[j];
        float aj = AR[j];
        float ltx = fmaxf(bi.x, bj.x), lty = fmaxf(bi.y, bj.y);
        float rbx = fminf(bi.z, bj.z), rby = fminf(bi.w, bj.w);
        float w = fmaxf(rbx - ltx, 0.0f), h = fmaxf(rby - lty, 0.0f);
        float inter = w * h;
        float iou = inter / (ai + aj - inter + 1e-16f);
        u64 m = __ballot(iou > NMS_T);
        if (lane == 0) rowmask[((size_t)b * NSEL + i) * NWORD + chunk] = m;
    }
}

// ------- Kernel 4: single-wave register NMS (no LDS, no barriers) -------
__global__ __launch_bounds__(64) void k_nms(const u64* __restrict__ rowmask,
                                            const float4* __restrict__ sel_box,
                                            const float* __restrict__ sel_score,
                                            const int* __restrict__ sel_cls,
                                            float* __restrict__ out) {
    int b = blockIdx.x;
    int lane = threadIdx.x;
    int wsel = lane & 31;
    const u64* RM = rowmask + (size_t)b * NSEL * NWORD;
    const float* SC = sel_score + (size_t)b * NSEL;

    // svalid: lane l holds valid word (l&31)
    u64 svalid = 0;
    for (int w = 0; w < NWORD; ++w) {
        bool p = SC[w * 64 + lane] >= 0.0f;
        u64 m = __ballot(p);
        if (wsel == w) svalid = m;
    }

    u64 ssup = 0;    // lane l holds suppressed word (l&31); halves stay in sync
    u64 kreg = 0;    // lane d holds keep word d (d < 32)

    // prefetch chunk-0 diag: lane t holds rowmask[t][0]
    u64 diag_next = RM[(size_t)lane * NWORD];

    for (int d = 0; d < NWORD; ++d) {
        u64 diag = diag_next;
        // issue next chunk's diag load early (latency hidden under this iter)
        int dn = (d + 1 < NWORD) ? d + 1 : d;
        diag_next = RM[((size_t)(dn * 64) + lane) * NWORD + dn];

        // broadcast suppression + valid words for this chunk
        u64 sup_d = __shfl(ssup, d);
        u64 val_d = __shfl(svalid, d);
        u64 avail = val_d & ~sup_d;

        // greedy resolve: iterate kept candidates only (uniform control flow)
        u64 k = 0;
        while (avail) {
            int t = __ffsll((long long)avail) - 1;
            u64 rowt = __shfl(diag, t);
            k |= (1ULL << t);
            avail &= ~((1ULL << t) | rowt);
        }
        if (lane == d) kreg = k;

        // gather kept rows (8 per round, duplicates harmless for OR)
        u64 m = k;
        int base_row = d * 64;
        while (m) {
            int t0 = __ffsll((long long)m) - 1;  u64 m1 = m & (m - 1);
            int t1 = m1 ? __ffsll((long long)m1) - 1 : t0;  u64 m2 = m1 ? (m1 & (m1 - 1)) : 0ULL;
            int t2 = m2 ? __ffsll((long long)m2) - 1 : t0;  u64 m3 = m2 ? (m2 & (m2 - 1)) : 0ULL;
            int t3 = m3 ? __ffsll((long long)m3) - 1 : t0;  u64 m4 = m3 ? (m3 & (m3 - 1)) : 0ULL;
            int t4 = m4 ? __ffsll((long long)m4) - 1 : t0;  u64 m5 = m4 ? (m4 & (m4 - 1)) : 0ULL;
            int t5 = m5 ? __ffsll((long long)m5) - 1 : t0;  u64 m6 = m5 ? (m5 & (m5 - 1)) : 0ULL;
            int t6 = m6 ? __ffsll((long long)m6) - 1 : t0;  u64 m7 = m6 ? (m6 & (m6 - 1)) : 0ULL;
            int t7 = m7 ? __ffsll((long long)m7) - 1 : t0;  m = m7 ? (m7 & (m7 - 1)) : 0ULL;
            u64 r0 = RM[(size_t)(base_row + t0) * NWORD + wsel];
            u64 r1 = RM[(size_t)(base_row + t1) * NWORD + wsel];
            u64 r2 = RM[(size_t)(base_row + t2) * NWORD + wsel];
            u64 r3 = RM[(size_t)(base_row + t3) * NWORD + wsel];
            u64 r4 = RM[(size_t)(base_row + t4) * NWORD + wsel];
            u64 r5 = RM[(size_t)(base_row + t5) * NWORD + wsel];
            u64 r6 = RM[(size_t)(base_row + t6) * NWORD + wsel];
            u64 r7 = RM[(size_t)(base_row + t7) * NWORD + wsel];
            ssup |= (r0 | r1) | (r2 | r3) | ((r4 | r5) | (r6 | r7));
        }
    }

    // ---- epilogue: compact kept entries (descending-score order) ----
    int cnt = (lane < NWORD) ? __popcll(kreg) : 0;
    int pre = cnt;
    #pragma unroll
    for (int dd = 1; dd < 64; dd <<= 1) {
        int o = __shfl_up(pre, dd);
        if (lane >= dd) pre += o;
    }
    int total = __shfl(pre, 63);
    int base = pre - cnt;
    float* OUT = out + (size_t)b * MAXDET * 6;
    if (lane < NWORD) {
        u64 m = kreg;
        int rr = 0;
        while (m) {
            int t = __ffsll((long long)m) - 1;
            m &= m - 1;
            int slot = base + rr; ++rr;
            if (slot < MAXDET) {
                int i = lane * 64 + t;
                size_t src = (size_t)b * NSEL + i;
                float4 bx = sel_box[src];
                float sc = SC[i];
                int c = sel_cls[src];
                float* o6 = OUT + slot * 6;
                o6[0] = bx.x; o6[1] = bx.y; o6[2] = bx.z; o6[3] = bx.w;
                o6[4] = sc; o6[5] = (float)c;
            }
        }
    }
    int start = total > MAXDET ? MAXDET : total;
    for (int s = start + lane; s < MAXDET; s += 64) {
        float* o6 = OUT + s * 6;
        o6[0] = 0.0f; o6[1] = 0.0f; o6[2] = 0.0f;
        o6[3] = 0.0f; o6[4] = 0.0f; o6[5] = 0.0f;
    }
}

// ---------------- Launcher ----------------
extern "C" void kernel_launch(void* const* d_in, const int* in_sizes, int n_in,
                              void* d_out, int out_size, void* d_ws, size_t ws_size,
                              hipStream_t stream) {
    const float* pred = (const float*)d_in[0];
    float* out = (float*)d_out;

    char* ws = (char*)d_ws;
    size_t off = 0;
    auto alloc = [&](size_t bytes) -> void* {
        void* p = ws + off;
        off += (bytes + 255) & ~(size_t)255;
        return p;
    };

    u64*    keys      = (u64*)   alloc((size_t)NBATCH * NSORT * 8);
    float4* boxes     = (float4*)alloc((size_t)NBATCH * NANCH * 16);
    int*    cls       = (int*)   alloc((size_t)NBATCH * NANCH * 4);
    float*  score     = (float*) alloc((size_t)NBATCH * NANCH * 4);
    float4* sel_box   = (float4*)alloc((size_t)NBATCH * NSEL * 16);
    float4* sel_sbox  = (float4*)alloc((size_t)NBATCH * NSEL * 16);
    float*  sel_area  = (float*) alloc((size_t)NBATCH * NSEL * 4);
    float*  sel_score = (float*) alloc((size_t)NBATCH * NSEL * 4);
    int*    sel_cls   = (int*)   alloc((size_t)NBATCH * NSEL * 4);
    u64*    rowmask   = (u64*)   alloc((size_t)NBATCH * NSEL * NWORD * 8);

    dim3 g1((NANCH + 127) / 128, NBATCH);
    k_prep<<<g1, 256, 0, stream>>>(pred, keys, boxes, cls, score);

    k_sel<<<NBATCH, 1024, 0, stream>>>(keys, boxes, cls, score,
                                       sel_box, sel_sbox, sel_area,
                                       sel_score, sel_cls);

    dim3 g3(NSEL, NBATCH);
    k_iou<<<g3, 256, 0, stream>>>(sel_sbox, sel_area, rowmask);

    k_nms<<<NBATCH, 64, 0, stream>>>(rowmask, sel_box, sel_score, sel_cls, out);
}

// Round 7
// 215.556 us; speedup vs baseline: 1.7954x; 1.7954x over previous
//
#include <hip/hip_runtime.h>
#include <hip/hip_bf16.h>
#include <stdint.h>

typedef unsigned long long u64;
typedef unsigned int u32;

#define NANCH 10647
#define NBATCH 16
#define NSORT 16384
#define NSEL 2048
#define NWORD 32
#define CONF_T 0.5f
#define NMS_T 0.5f
#define MAXDET 300
#define MAXWH 4096.0f

// ---------------- Kernel 1: per-anchor prep ----------------
__global__ __launch_bounds__(256) void k_prep(const float* __restrict__ pred,
                                              u64* __restrict__ keys,
                                              float4* __restrict__ boxes,
                                              int* __restrict__ cls,
                                              float* __restrict__ score) {
    __shared__ float sm[128 * 85];
    int b = blockIdx.y;
    int a0 = blockIdx.x * 128;
    int na = NANCH - a0; if (na > 128) na = 128;
    const float* src = pred + ((size_t)b * NANCH + a0) * 85;
    int tot = na * 85;
    for (int i = threadIdx.x; i < tot; i += 256) sm[i] = src[i];
    __syncthreads();
    int t = threadIdx.x;
    if (t < na) {
        const float* s = &sm[t * 85];
        float x = s[0], y = s[1], w = s[2], h = s[3], obj = s[4];
        float best = s[5] * obj; int arg = 0;
        #pragma unroll
        for (int c = 1; c < 80; ++c) {
            float v = s[5 + c] * obj;
            if (v > best) { best = v; arg = c; }
        }
        bool valid = obj >= CONF_T;
        float sc = valid ? best : -1.0f;
        int a = a0 + t;
        float4 bx;
        bx.x = x - w * 0.5f; bx.y = y - h * 0.5f;
        bx.z = x + w * 0.5f; bx.w = y + h * 0.5f;
        size_t o = (size_t)b * NANCH + a;
        boxes[o] = bx;
        cls[o] = arg;
        score[o] = sc;
        u32 u = __float_as_uint(sc);
        u32 v = (u & 0x80000000u) ? ~u : (u | 0x80000000u); // ascending map
        u32 hi = ~v;                                        // descending
        keys[(size_t)b * NSORT + a] = ((u64)hi << 32) | (u32)a;
    }
}

// ------- Kernel 2: radix-select top-2048 + bitonic sort + gather -------
__global__ __launch_bounds__(1024) void k_sel(const u64* __restrict__ keys,
                                              const float4* __restrict__ boxes,
                                              const int* __restrict__ cls,
                                              const float* __restrict__ score,
                                              float4* __restrict__ sel_box,
                                              float4* __restrict__ sel_sbox,
                                              float* __restrict__ sel_area,
                                              float* __restrict__ sel_score,
                                              int* __restrict__ sel_cls) {
    __shared__ u64 sk[NSEL];        // 16 KB
    __shared__ u32 hist[256];
    __shared__ u32 hsc[256];
    __shared__ u64 s_P;             // known-prefix value
    __shared__ u64 s_M;             // known-prefix mask
    __shared__ u32 s_rank;
    __shared__ u32 s_cnt;

    int b = blockIdx.x;
    int tid = threadIdx.x;
    const u64* KB = keys + (size_t)b * NSORT;

    if (tid == 0) { s_P = 0; s_M = 0; s_rank = NSEL; s_cnt = 0; }
    __syncthreads();

    // ---- Phase A: radix-select the 2048th-smallest key ----
    const int shifts[6] = {56, 48, 40, 32, 8, 0};
    for (int r = 0; r < 6; ++r) {
        int shift = shifts[r];
        if (tid < 256) hist[tid] = 0;
        __syncthreads();
        u64 P = s_P, M = s_M;
        for (int i = tid; i < NANCH; i += 1024) {
            u64 key = KB[i];
            if ((key & M) == P)
                atomicAdd(&hist[(u32)(key >> shift) & 0xFFu], 1u);
        }
        __syncthreads();
        if (tid < 256) hsc[tid] = hist[tid];
        __syncthreads();
        for (int d = 1; d < 256; d <<= 1) {
            u32 add = 0;
            if (tid < 256 && tid >= d) add = hsc[tid - d];
            __syncthreads();
            if (tid < 256) hsc[tid] += add;
            __syncthreads();
        }
        if (tid < 256) {
            u32 rank = s_rank;
            u32 inc = hsc[tid];
            u32 cb = inc - hist[tid];
            if (cb < rank && rank <= inc) {
                s_rank = rank - cb;
                s_P = s_P | ((u64)tid << shift);
                s_M = s_M | (0xFFull << shift);
            }
        }
        __syncthreads();
    }
    u64 T = s_P;

    // ---- Phase B: compact the 2048 keys <= T into LDS ----
    for (int i = tid; i < NANCH; i += 1024) {
        u64 key = KB[i];
        if (key <= T) {
            u32 pos = atomicAdd(&s_cnt, 1u);
            sk[pos] = key;
        }
    }
    __syncthreads();

    // ---- Phase C: bitonic sort 2048 keys ascending ----
    for (int k = 2; k <= NSEL; k <<= 1) {
        for (int j = k >> 1; j > 0; j >>= 1) {
            int n = tid;
            int i = ((n & ~(j - 1)) << 1) | (n & (j - 1));
            int l = i | j;
            u64 a = sk[i], c = sk[l];
            bool up = ((i & k) == 0);
            if ((a > c) == up) { sk[i] = c; sk[l] = a; }
            __syncthreads();
        }
    }

    // ---- Phase D: gather selected entries ----
    for (int r = tid; r < NSEL; r += 1024) {
        u64 key = sk[r];
        int a = (int)(key & 0xFFFFFFFFu);
        size_t src = (size_t)b * NANCH + a;
        float4 bx = boxes[src];
        int c = cls[src];
        float sc = score[src];
        float off = (float)c * MAXWH;
        float4 sb;
        sb.x = bx.x + off; sb.y = bx.y + off;
        sb.z = bx.z + off; sb.w = bx.w + off;
        float area = (sb.z - sb.x) * (sb.w - sb.y);
        size_t o = (size_t)b * NSEL + r;
        sel_box[o] = bx; sel_sbox[o] = sb; sel_area[o] = area;
        sel_score[o] = sc; sel_cls[o] = c;
    }
}

// ---- Kernel 3: lower-triangle IoU bitmask, tiled (32 row-chunks x 16) ----
__global__ __launch_bounds__(1024) void k_iou(const float4* __restrict__ sel_sbox,
                                              const float* __restrict__ sel_area,
                                              u64* __restrict__ rowmask) {
    __shared__ float4 sbx[NSEL];    // 32 KB
    __shared__ float  sar[NSEL];    // 8 KB
    int rch = blockIdx.x;           // row chunk 0..31
    int b = blockIdx.y;
    int tid = threadIdx.x, lane = tid & 63, wv = tid >> 6;   // 16 waves
    const float4* SB = sel_sbox + (size_t)b * NSEL;
    const float* AR = sel_area + (size_t)b * NSEL;
    int ncol = (rch + 1) * 64;
    for (int j = tid; j < ncol; j += 1024) { sbx[j] = SB[j]; sar[j] = AR[j]; }
    __syncthreads();
    u64* RMB = rowmask + ((size_t)b * NSEL + (size_t)rch * 64) * NWORD;
    for (int w = wv; w <= rch; w += 16) {
        int j = w * 64 + lane;
        float4 bj = sbx[j];
        float aj = sar[j];
        for (int t = 0; t < 64; ++t) {
            float4 bi = sbx[rch * 64 + t];   // LDS broadcast
            float ai = sar[rch * 64 + t];
            float ltx = fmaxf(bi.x, bj.x), lty = fmaxf(bi.y, bj.y);
            float rbx = fminf(bi.z, bj.z), rby = fminf(bi.w, bj.w);
            float ww = fmaxf(rbx - ltx, 0.0f), hh = fmaxf(rby - lty, 0.0f);
            float inter = ww * hh;
            float iou = inter / (ai + aj - inter + 1e-16f);
            u64 m = __ballot(iou > NMS_T);
            if (lane == 0) RMB[(size_t)t * NWORD + w] = m;
        }
    }
}

// ---- Kernel 4: pipelined chunk NMS: resolve || hit-test || prefetch ----
__global__ __launch_bounds__(512) void k_nms(const u64* __restrict__ rowmask,
                                             const float4* __restrict__ sel_box,
                                             const float* __restrict__ sel_score,
                                             const int* __restrict__ sel_cls,
                                             float* __restrict__ out) {
    __shared__ u64 sblk[2][64][33];   // [buf][row][word], padded; 33.8 KB
    __shared__ u64 skeep[NWORD];
    __shared__ u64 svalid[NWORD];
    __shared__ u64 s_pend;
    __shared__ u64 s_hit;
    __shared__ u32 s_total;

    int b = blockIdx.x;
    int tid = threadIdx.x, lane = tid & 63, wv = tid >> 6;   // 8 waves
    const u64* RM = rowmask + (size_t)b * NSEL * NWORD;
    const float* SC = sel_score + (size_t)b * NSEL;

    for (int w = wv; w < NWORD; w += 8) {
        bool p = SC[w * 64 + lane] >= 0.0f;
        u64 m = __ballot(p);
        if (lane == 0) svalid[w] = m;
    }
    if (tid < NWORD) skeep[tid] = 0ULL;
    if (tid == 0) s_hit = 0ULL;

    int r = tid >> 3, w0 = (tid & 7) * 4;   // each thread: row r, words w0..w0+3
    // load chunk 0 (only word 0 needed; load 4 words where w0==0)
    if (w0 == 0) {
        const u64* src = RM + (size_t)r * NWORD;
        ulonglong2 a = *(const ulonglong2*)src;
        ulonglong2 c = *(const ulonglong2*)(src + 2);
        sblk[0][r][0] = a.x; sblk[0][r][1] = a.y;
        sblk[0][r][2] = c.x; sblk[0][r][3] = c.y;
    }
    // issue prefetch for chunk 1 (words w0 <= 1)
    ulonglong2 pa, pc;
    if (w0 <= 1) {
        const u64* src = RM + (size_t)NSEL + (size_t)r * NWORD + w0;
        pa = *(const ulonglong2*)src;
        pc = *(const ulonglong2*)(src + 2);
    }
    __syncthreads();
    if (tid == 0) s_pend = svalid[0];

    u64 kreg = 0;
    for (int d = 0; d < NWORD; ++d) {
        int cur = d & 1, nxt = cur ^ 1;
        // phase 1: commit prefetched chunk d+1 to LDS; issue loads for d+2
        if (d + 1 < NWORD && w0 <= d + 1) {
            sblk[nxt][r][w0 + 0] = pa.x; sblk[nxt][r][w0 + 1] = pa.y;
            sblk[nxt][r][w0 + 2] = pc.x; sblk[nxt][r][w0 + 3] = pc.y;
        }
        if (d + 2 < NWORD && w0 <= d + 2) {
            const u64* src = RM + (size_t)(d + 2) * 2048 + (size_t)r * NWORD + w0;
            pa = *(const ulonglong2*)src;
            pc = *(const ulonglong2*)(src + 2);
        }
        __syncthreads();
        // phase 2: wave 0 resolves chunk d; waves 1-7 hit-test chunk d+1 (c<d)
        u64 kq = 0;
        if (wv == 0) {
            u64 pend = s_pend;
            u64 k = 0;
            #pragma unroll 8
            for (int t = 0; t < 64; ++t) {
                u64 rowt = sblk[cur][t][d];    // LDS broadcast, k-independent addr
                bool kt = (((pend >> t) & 1ULL) != 0ULL) & ((rowt & k) == 0ULL);
                k |= ((u64)kt) << t;
            }
            if (lane == 0) skeep[d] = k;
            if (lane == d) kreg = k;
            kq = k;
        } else if (d + 1 < NWORD) {
            bool hit = false;
            for (int c = wv - 1; c < d; c += 7)
                hit = hit | ((sblk[nxt][lane][c] & skeep[c]) != 0ULL);
            u64 hm = __ballot(hit);
            if (lane == 0 && hm) atomicOr(&s_hit, hm);
        }
        __syncthreads();
        // phase 3: wave 0 finalizes pend(d+1) with the c=d term; resets s_hit
        if (wv == 0 && d + 1 < NWORD) {
            u64 rowd = sblk[nxt][lane][d];
            u64 hitfix = __ballot((rowd & kq) != 0ULL);
            if (lane == 0) {
                s_pend = svalid[d + 1] & ~s_hit & ~hitfix;
                s_hit = 0ULL;
            }
        }
    }

    // ---- epilogue: compact kept entries (descending-score order) ----
    if (wv == 0) {
        int cnt = (lane < NWORD) ? __popcll(kreg) : 0;
        int pre = cnt;
        #pragma unroll
        for (int dd = 1; dd < 64; dd <<= 1) {
            int o = __shfl_up(pre, dd);
            if (lane >= dd) pre += o;
        }
        int total = __shfl(pre, 63);
        int base = pre - cnt;
        float* OUT = out + (size_t)b * MAXDET * 6;
        if (lane < NWORD) {
            u64 m = kreg;
            int rr = 0;
            while (m) {
                int t = __ffsll((long long)m) - 1;
                m &= m - 1;
                int slot = base + rr; ++rr;
                if (slot < MAXDET) {
                    int i = lane * 64 + t;
                    size_t src = (size_t)b * NSEL + i;
                    float4 bx = sel_box[src];
                    float sc = SC[i];
                    int c = sel_cls[src];
                    float* o6 = OUT + slot * 6;
                    o6[0] = bx.x; o6[1] = bx.y; o6[2] = bx.z; o6[3] = bx.w;
                    o6[4] = sc; o6[5] = (float)c;
                }
            }
        }
        if (lane == 0) s_total = (total > MAXDET) ? MAXDET : total;
    }
    __syncthreads();
    int start = (int)s_total;
    float* OUT = out + (size_t)b * MAXDET * 6;
    for (int s = start + tid; s < MAXDET; s += 512) {
        float* o6 = OUT + s * 6;
        o6[0] = 0.0f; o6[1] = 0.0f; o6[2] = 0.0f;
        o6[3] = 0.0f; o6[4] = 0.0f; o6[5] = 0.0f;
    }
}

// ---------------- Launcher ----------------
extern "C" void kernel_launch(void* const* d_in, const int* in_sizes, int n_in,
                              void* d_out, int out_size, void* d_ws, size_t ws_size,
                              hipStream_t stream) {
    const float* pred = (const float*)d_in[0];
    float* out = (float*)d_out;

    char* ws = (char*)d_ws;
    size_t off = 0;
    auto alloc = [&](size_t bytes) -> void* {
        void* p = ws + off;
        off += (bytes + 255) & ~(size_t)255;
        return p;
    };

    u64*    keys      = (u64*)   alloc((size_t)NBATCH * NSORT * 8);
    float4* boxes     = (float4*)alloc((size_t)NBATCH * NANCH * 16);
    int*    cls       = (int*)   alloc((size_t)NBATCH * NANCH * 4);
    float*  score     = (float*) alloc((size_t)NBATCH * NANCH * 4);
    float4* sel_box   = (float4*)alloc((size_t)NBATCH * NSEL * 16);
    float4* sel_sbox  = (float4*)alloc((size_t)NBATCH * NSEL * 16);
    float*  sel_area  = (float*) alloc((size_t)NBATCH * NSEL * 4);
    float*  sel_score = (float*) alloc((size_t)NBATCH * NSEL * 4);
    int*    sel_cls   = (int*)   alloc((size_t)NBATCH * NSEL * 4);
    u64*    rowmask   = (u64*)   alloc((size_t)NBATCH * NSEL * NWORD * 8);

    dim3 g1((NANCH + 127) / 128, NBATCH);
    k_prep<<<g1, 256, 0, stream>>>(pred, keys, boxes, cls, score);

    k_sel<<<NBATCH, 1024, 0, stream>>>(keys, boxes, cls, score,
                                       sel_box, sel_sbox, sel_area,
                                       sel_score, sel_cls);

    dim3 g3(NWORD, NBATCH);
    k_iou<<<g3, 1024, 0, stream>>>(sel_sbox, sel_area, rowmask);

    k_nms<<<NBATCH, 512, 0, stream>>>(rowmask, sel_box, sel_score, sel_cls, out);
}

// Round 8
// 147.638 us; speedup vs baseline: 2.6214x; 1.4600x over previous
//
#include <hip/hip_runtime.h>
#include <hip/hip_bf16.h>
#include <stdint.h>

typedef unsigned long long u64;
typedef unsigned int u32;

#define NANCH 10647
#define NBATCH 16
#define NSORT 16384
#define NSEL 2048
#define NWORD 32
#define CONF_T 0.5f
#define NMS_T 0.5f
#define MAXDET 300
#define MAXWH 4096.0f

// ---------------- Kernel 1: per-anchor prep ----------------
__global__ __launch_bounds__(256) void k_prep(const float* __restrict__ pred,
                                              u64* __restrict__ keys,
                                              float4* __restrict__ boxes,
                                              int* __restrict__ cls,
                                              float* __restrict__ score) {
    __shared__ float sm[128 * 85];
    int b = blockIdx.y;
    int a0 = blockIdx.x * 128;
    int na = NANCH - a0; if (na > 128) na = 128;
    const float* src = pred + ((size_t)b * NANCH + a0) * 85;
    int tot = na * 85;
    for (int i = threadIdx.x; i < tot; i += 256) sm[i] = src[i];
    __syncthreads();
    int t = threadIdx.x;
    if (t < na) {
        const float* s = &sm[t * 85];
        float x = s[0], y = s[1], w = s[2], h = s[3], obj = s[4];
        float best = s[5] * obj; int arg = 0;
        #pragma unroll
        for (int c = 1; c < 80; ++c) {
            float v = s[5 + c] * obj;
            if (v > best) { best = v; arg = c; }
        }
        bool valid = obj >= CONF_T;
        float sc = valid ? best : -1.0f;
        int a = a0 + t;
        float4 bx;
        bx.x = x - w * 0.5f; bx.y = y - h * 0.5f;
        bx.z = x + w * 0.5f; bx.w = y + h * 0.5f;
        size_t o = (size_t)b * NANCH + a;
        boxes[o] = bx;
        cls[o] = arg;
        score[o] = sc;
        u32 u = __float_as_uint(sc);
        u32 v = (u & 0x80000000u) ? ~u : (u | 0x80000000u); // ascending map
        u32 hi = ~v;                                        // descending
        keys[(size_t)b * NSORT + a] = ((u64)hi << 32) | (u32)a;
    }
}

// ------- Kernel 2: radix-select top-2048 + bitonic sort + gather -------
__global__ __launch_bounds__(1024) void k_sel(const u64* __restrict__ keys,
                                              const float4* __restrict__ boxes,
                                              const int* __restrict__ cls,
                                              const float* __restrict__ score,
                                              float4* __restrict__ sel_box,
                                              float4* __restrict__ sel_sbox,
                                              float* __restrict__ sel_area,
                                              float* __restrict__ sel_score,
                                              int* __restrict__ sel_cls) {
    __shared__ u64 sk[NSEL];        // 16 KB
    __shared__ u32 hist[256];
    __shared__ u32 hsc[256];
    __shared__ u64 s_P;             // known-prefix value
    __shared__ u64 s_M;             // known-prefix mask
    __shared__ u32 s_rank;
    __shared__ u32 s_cnt;

    int b = blockIdx.x;
    int tid = threadIdx.x;
    const u64* KB = keys + (size_t)b * NSORT;

    if (tid == 0) { s_P = 0; s_M = 0; s_rank = NSEL; s_cnt = 0; }
    __syncthreads();

    // ---- Phase A: radix-select the 2048th-smallest key ----
    const int shifts[6] = {56, 48, 40, 32, 8, 0};
    for (int r = 0; r < 6; ++r) {
        int shift = shifts[r];
        if (tid < 256) hist[tid] = 0;
        __syncthreads();
        u64 P = s_P, M = s_M;
        for (int i = tid; i < NANCH; i += 1024) {
            u64 key = KB[i];
            if ((key & M) == P)
                atomicAdd(&hist[(u32)(key >> shift) & 0xFFu], 1u);
        }
        __syncthreads();
        if (tid < 256) hsc[tid] = hist[tid];
        __syncthreads();
        for (int d = 1; d < 256; d <<= 1) {
            u32 add = 0;
            if (tid < 256 && tid >= d) add = hsc[tid - d];
            __syncthreads();
            if (tid < 256) hsc[tid] += add;
            __syncthreads();
        }
        if (tid < 256) {
            u32 rank = s_rank;
            u32 inc = hsc[tid];
            u32 cb = inc - hist[tid];
            if (cb < rank && rank <= inc) {
                s_rank = rank - cb;
                s_P = s_P | ((u64)tid << shift);
                s_M = s_M | (0xFFull << shift);
            }
        }
        __syncthreads();
    }
    u64 T = s_P;

    // ---- Phase B: compact the 2048 keys <= T into LDS ----
    for (int i = tid; i < NANCH; i += 1024) {
        u64 key = KB[i];
        if (key <= T) {
            u32 pos = atomicAdd(&s_cnt, 1u);
            sk[pos] = key;
        }
    }
    __syncthreads();

    // ---- Phase C: bitonic sort 2048 keys ascending ----
    for (int k = 2; k <= NSEL; k <<= 1) {
        for (int j = k >> 1; j > 0; j >>= 1) {
            int n = tid;
            int i = ((n & ~(j - 1)) << 1) | (n & (j - 1));
            int l = i | j;
            u64 a = sk[i], c = sk[l];
            bool up = ((i & k) == 0);
            if ((a > c) == up) { sk[i] = c; sk[l] = a; }
            __syncthreads();
        }
    }

    // ---- Phase D: gather selected entries ----
    for (int r = tid; r < NSEL; r += 1024) {
        u64 key = sk[r];
        int a = (int)(key & 0xFFFFFFFFu);
        size_t src = (size_t)b * NANCH + a;
        float4 bx = boxes[src];
        int c = cls[src];
        float sc = score[src];
        float off = (float)c * MAXWH;
        float4 sb;
        sb.x = bx.x + off; sb.y = bx.y + off;
        sb.z = bx.z + off; sb.w = bx.w + off;
        float area = (sb.z - sb.x) * (sb.w - sb.y);
        size_t o = (size_t)b * NSEL + r;
        sel_box[o] = bx; sel_sbox[o] = sb; sel_area[o] = area;
        sel_score[o] = sc; sel_cls[o] = c;
    }
}

// ---- Kernel 3: lower-triangle IoU bitmask, tiled (32 row-chunks x 16) ----
__global__ __launch_bounds__(1024) void k_iou(const float4* __restrict__ sel_sbox,
                                              const float* __restrict__ sel_area,
                                              u64* __restrict__ rowmask) {
    __shared__ float4 sbx[NSEL];    // 32 KB
    __shared__ float  sar[NSEL];    // 8 KB
    int rch = blockIdx.x;           // row chunk 0..31
    int b = blockIdx.y;
    int tid = threadIdx.x, lane = tid & 63, wv = tid >> 6;   // 16 waves
    const float4* SB = sel_sbox + (size_t)b * NSEL;
    const float* AR = sel_area + (size_t)b * NSEL;
    int ncol = (rch + 1) * 64;
    for (int j = tid; j < ncol; j += 1024) { sbx[j] = SB[j]; sar[j] = AR[j]; }
    __syncthreads();
    u64* RMB = rowmask + ((size_t)b * NSEL + (size_t)rch * 64) * NWORD;
    for (int w = wv; w <= rch; w += 16) {
        int j = w * 64 + lane;
        float4 bj = sbx[j];
        float aj = sar[j];
        for (int t = 0; t < 64; ++t) {
            float4 bi = sbx[rch * 64 + t];   // LDS broadcast
            float ai = sar[rch * 64 + t];
            float ltx = fmaxf(bi.x, bj.x), lty = fmaxf(bi.y, bj.y);
            float rbx = fminf(bi.z, bj.z), rby = fminf(bi.w, bj.w);
            float ww = fmaxf(rbx - ltx, 0.0f), hh = fmaxf(rby - lty, 0.0f);
            float inter = ww * hh;
            float iou = inter / (ai + aj - inter + 1e-16f);
            u64 m = __ballot(iou > NMS_T);
            if (lane == 0) RMB[(size_t)t * NWORD + w] = m;
        }
    }
}

// ---- Kernel 4: pipelined chunk NMS: peel-resolve || hit-test || prefetch ----
__global__ __launch_bounds__(512) void k_nms(const u64* __restrict__ rowmask,
                                             const float4* __restrict__ sel_box,
                                             const float* __restrict__ sel_score,
                                             const int* __restrict__ sel_cls,
                                             float* __restrict__ out) {
    __shared__ u64 sblk[2][64][33];   // [buf][row][word], padded; 33.8 KB
    __shared__ u64 skeep[NWORD];
    __shared__ u64 svalid[NWORD];
    __shared__ u64 s_pend;
    __shared__ u64 s_hit;
    __shared__ u32 s_total;

    int b = blockIdx.x;
    int tid = threadIdx.x, lane = tid & 63, wv = tid >> 6;   // 8 waves
    const u64* RM = rowmask + (size_t)b * NSEL * NWORD;
    const float* SC = sel_score + (size_t)b * NSEL;

    for (int w = wv; w < NWORD; w += 8) {
        bool p = SC[w * 64 + lane] >= 0.0f;
        u64 m = __ballot(p);
        if (lane == 0) svalid[w] = m;
    }
    if (tid < NWORD) skeep[tid] = 0ULL;
    if (tid == 0) s_hit = 0ULL;

    int r = tid >> 3, w0 = (tid & 7) * 4;   // each thread: row r, words w0..w0+3
    // load chunk 0 (only word 0 needed; load 4 words where w0==0)
    if (w0 == 0) {
        const u64* src = RM + (size_t)r * NWORD;
        ulonglong2 a = *(const ulonglong2*)src;
        ulonglong2 c = *(const ulonglong2*)(src + 2);
        sblk[0][r][0] = a.x; sblk[0][r][1] = a.y;
        sblk[0][r][2] = c.x; sblk[0][r][3] = c.y;
    }
    // issue prefetch for chunk 1 (words w0 <= 1)
    ulonglong2 pa, pc;
    if (w0 <= 1) {
        const u64* src = RM + (size_t)NSEL + (size_t)r * NWORD + w0;
        pa = *(const ulonglong2*)src;
        pc = *(const ulonglong2*)(src + 2);
    }
    __syncthreads();
    if (tid == 0) s_pend = svalid[0];

    u64 kreg = 0;
    for (int d = 0; d < NWORD; ++d) {
        int cur = d & 1, nxt = cur ^ 1;
        // phase 1: commit prefetched chunk d+1 to LDS; issue loads for d+2
        if (d + 1 < NWORD && w0 <= d + 1) {
            sblk[nxt][r][w0 + 0] = pa.x; sblk[nxt][r][w0 + 1] = pa.y;
            sblk[nxt][r][w0 + 2] = pc.x; sblk[nxt][r][w0 + 3] = pc.y;
        }
        if (d + 2 < NWORD && w0 <= d + 2) {
            const u64* src = RM + (size_t)(d + 2) * 2048 + (size_t)r * NWORD + w0;
            pa = *(const ulonglong2*)src;
            pc = *(const ulonglong2*)(src + 2);
        }
        __syncthreads();
        // phase 2: wave 0 resolves chunk d by parallel peeling (symmetric IoU
        // matrix => within-chunk greedy == lexicographically-first MIS);
        // waves 1-7 hit-test chunk d+1 (c<d)
        u64 kq = 0;
        if (wv == 0) {
            u64 Rt = sblk[cur][lane][d];   // row `lane` of the diagonal block
            u64 below = (1ULL << lane) - 1ULL;   // bits s < lane
            u64 U = s_pend;                // undecided set (uniform)
            u64 kept = 0;
            // Peel: keep every t in U with no earlier undecided neighbor.
            // t in U implies t has no earlier KEPT neighbor (it would have
            // been removed when that neighbor was kept, via symmetry), so
            // all its earlier neighbors decided-not-kept => greedy keeps t.
            // A newly-kept s cannot kill an earlier t in U (s would have had
            // an earlier undecided neighbor), so killing via full row is safe.
            while (U) {
                bool inU = ((U >> lane) & 1ULL) != 0ULL;
                u64 newk = __ballot(inU && ((Rt & U & below) == 0ULL));
                u64 killed = __ballot((Rt & newk) != 0ULL);
                kept |= newk;
                U &= ~(newk | killed);
            }
            if (lane == 0) skeep[d] = kept;
            if (lane == d) kreg = kept;
            kq = kept;
        } else if (d + 1 < NWORD) {
            bool hit = false;
            for (int c = wv - 1; c < d; c += 7)
                hit = hit | ((sblk[nxt][lane][c] & skeep[c]) != 0ULL);
            u64 hm = __ballot(hit);
            if (lane == 0 && hm) atomicOr(&s_hit, hm);
        }
        __syncthreads();
        // phase 3: wave 0 finalizes pend(d+1) with the c=d term; resets s_hit
        if (wv == 0 && d + 1 < NWORD) {
            u64 rowd = sblk[nxt][lane][d];
            u64 hitfix = __ballot((rowd & kq) != 0ULL);
            if (lane == 0) {
                s_pend = svalid[d + 1] & ~s_hit & ~hitfix;
                s_hit = 0ULL;
            }
        }
    }

    // ---- epilogue: compact kept entries (descending-score order) ----
    if (wv == 0) {
        int cnt = (lane < NWORD) ? __popcll(kreg) : 0;
        int pre = cnt;
        #pragma unroll
        for (int dd = 1; dd < 64; dd <<= 1) {
            int o = __shfl_up(pre, dd);
            if (lane >= dd) pre += o;
        }
        int total = __shfl(pre, 63);
        int base = pre - cnt;
        float* OUT = out + (size_t)b * MAXDET * 6;
        if (lane < NWORD) {
            u64 m = kreg;
            int rr = 0;
            while (m) {
                int t = __ffsll((long long)m) - 1;
                m &= m - 1;
                int slot = base + rr; ++rr;
                if (slot < MAXDET) {
                    int i = lane * 64 + t;
                    size_t src = (size_t)b * NSEL + i;
                    float4 bx = sel_box[src];
                    float sc = SC[i];
                    int c = sel_cls[src];
                    float* o6 = OUT + slot * 6;
                    o6[0] = bx.x; o6[1] = bx.y; o6[2] = bx.z; o6[3] = bx.w;
                    o6[4] = sc; o6[5] = (float)c;
                }
            }
        }
        if (lane == 0) s_total = (total > MAXDET) ? MAXDET : total;
    }
    __syncthreads();
    int start = (int)s_total;
    float* OUT = out + (size_t)b * MAXDET * 6;
    for (int s = start + tid; s < MAXDET; s += 512) {
        float* o6 = OUT + s * 6;
        o6[0] = 0.0f; o6[1] = 0.0f; o6[2] = 0.0f;
        o6[3] = 0.0f; o6[4] = 0.0f; o6[5] = 0.0f;
    }
}

// ---------------- Launcher ----------------
extern "C" void kernel_launch(void* const* d_in, const int* in_sizes, int n_in,
                              void* d_out, int out_size, void* d_ws, size_t ws_size,
                              hipStream_t stream) {
    const float* pred = (const float*)d_in[0];
    float* out = (float*)d_out;

    char* ws = (char*)d_ws;
    size_t off = 0;
    auto alloc = [&](size_t bytes) -> void* {
        void* p = ws + off;
        off += (bytes + 255) & ~(size_t)255;
        return p;
    };

    u64*    keys      = (u64*)   alloc((size_t)NBATCH * NSORT * 8);
    float4* boxes     = (float4*)alloc((size_t)NBATCH * NANCH * 16);
    int*    cls       = (int*)   alloc((size_t)NBATCH * NANCH * 4);
    float*  score     = (float*) alloc((size_t)NBATCH * NANCH * 4);
    float4* sel_box   = (float4*)alloc((size_t)NBATCH * NSEL * 16);
    float4* sel_sbox  = (float4*)alloc((size_t)NBATCH * NSEL * 16);
    float*  sel_area  = (float*) alloc((size_t)NBATCH * NSEL * 4);
    float*  sel_score = (float*) alloc((size_t)NBATCH * NSEL * 4);
    int*    sel_cls   = (int*)   alloc((size_t)NBATCH * NSEL * 4);
    u64*    rowmask   = (u64*)   alloc((size_t)NBATCH * NSEL * NWORD * 8);

    dim3 g1((NANCH + 127) / 128, NBATCH);
    k_prep<<<g1, 256, 0, stream>>>(pred, keys, boxes, cls, score);

    k_sel<<<NBATCH, 1024, 0, stream>>>(keys, boxes, cls, score,
                                       sel_box, sel_sbox, sel_area,
                                       sel_score, sel_cls);

    dim3 g3(NWORD, NBATCH);
    k_iou<<<g3, 1024, 0, stream>>>(sel_sbox, sel_area, rowmask);

    k_nms<<<NBATCH, 512, 0, stream>>>(rowmask, sel_box, sel_score, sel_cls, out);
}

// Round 9
// 112.279 us; speedup vs baseline: 3.4469x; 1.3149x over previous
//
#include <hip/hip_runtime.h>
#include <hip/hip_bf16.h>
#include <stdint.h>

typedef unsigned long long u64;
typedef unsigned int u32;
typedef unsigned short u16;

#define NANCH 10647
#define NBATCH 16
#define NSORT 16384
#define NSEL 2048
#define NWORD 32
#define NCLS 80
#define CONF_T 0.5f
#define NMS_T 0.5f
#define MAXDET 300
#define MAXWH 4096.0f

// ---------------- Kernel 1: per-anchor prep ----------------
__global__ __launch_bounds__(256) void k_prep(const float* __restrict__ pred,
                                              u64* __restrict__ keys,
                                              float4* __restrict__ boxes,
                                              int* __restrict__ cls,
                                              float* __restrict__ score) {
    __shared__ float sm[128 * 85];
    int b = blockIdx.y;
    int a0 = blockIdx.x * 128;
    int na = NANCH - a0; if (na > 128) na = 128;
    const float* src = pred + ((size_t)b * NANCH + a0) * 85;
    int tot = na * 85;
    for (int i = threadIdx.x; i < tot; i += 256) sm[i] = src[i];
    __syncthreads();
    int t = threadIdx.x;
    if (t < na) {
        const float* s = &sm[t * 85];
        float x = s[0], y = s[1], w = s[2], h = s[3], obj = s[4];
        float best = s[5] * obj; int arg = 0;
        #pragma unroll
        for (int c = 1; c < 80; ++c) {
            float v = s[5 + c] * obj;
            if (v > best) { best = v; arg = c; }
        }
        bool valid = obj >= CONF_T;
        float sc = valid ? best : -1.0f;
        int a = a0 + t;
        float4 bx;
        bx.x = x - w * 0.5f; bx.y = y - h * 0.5f;
        bx.z = x + w * 0.5f; bx.w = y + h * 0.5f;
        size_t o = (size_t)b * NANCH + a;
        boxes[o] = bx;
        cls[o] = arg;
        score[o] = sc;
        u32 u = __float_as_uint(sc);
        u32 v = (u & 0x80000000u) ? ~u : (u | 0x80000000u); // ascending map
        u32 hi = ~v;                                        // descending
        keys[(size_t)b * NSORT + a] = ((u64)hi << 32) | (u32)a;
    }
}

// ------- Kernel 2: radix-select top-2048 + bitonic sort + gather -------
__global__ __launch_bounds__(1024) void k_sel(const u64* __restrict__ keys,
                                              const float4* __restrict__ boxes,
                                              const int* __restrict__ cls,
                                              const float* __restrict__ score,
                                              float4* __restrict__ sel_box,
                                              float4* __restrict__ sel_sbox,
                                              float* __restrict__ sel_area,
                                              float* __restrict__ sel_score,
                                              int* __restrict__ sel_cls) {
    __shared__ u64 sk[NSEL];        // 16 KB
    __shared__ u32 hist[256];
    __shared__ u32 hsc[256];
    __shared__ u64 s_P;             // known-prefix value
    __shared__ u64 s_M;             // known-prefix mask
    __shared__ u32 s_rank;
    __shared__ u32 s_cnt;

    int b = blockIdx.x;
    int tid = threadIdx.x;
    const u64* KB = keys + (size_t)b * NSORT;

    if (tid == 0) { s_P = 0; s_M = 0; s_rank = NSEL; s_cnt = 0; }
    __syncthreads();

    // ---- Phase A: radix-select the 2048th-smallest key ----
    const int shifts[6] = {56, 48, 40, 32, 8, 0};
    for (int r = 0; r < 6; ++r) {
        int shift = shifts[r];
        if (tid < 256) hist[tid] = 0;
        __syncthreads();
        u64 P = s_P, M = s_M;
        for (int i = tid; i < NANCH; i += 1024) {
            u64 key = KB[i];
            if ((key & M) == P)
                atomicAdd(&hist[(u32)(key >> shift) & 0xFFu], 1u);
        }
        __syncthreads();
        if (tid < 256) hsc[tid] = hist[tid];
        __syncthreads();
        for (int d = 1; d < 256; d <<= 1) {
            u32 add = 0;
            if (tid < 256 && tid >= d) add = hsc[tid - d];
            __syncthreads();
            if (tid < 256) hsc[tid] += add;
            __syncthreads();
        }
        if (tid < 256) {
            u32 rank = s_rank;
            u32 inc = hsc[tid];
            u32 cb = inc - hist[tid];
            if (cb < rank && rank <= inc) {
                s_rank = rank - cb;
                s_P = s_P | ((u64)tid << shift);
                s_M = s_M | (0xFFull << shift);
            }
        }
        __syncthreads();
    }
    u64 T = s_P;

    // ---- Phase B: compact the 2048 keys <= T into LDS ----
    for (int i = tid; i < NANCH; i += 1024) {
        u64 key = KB[i];
        if (key <= T) {
            u32 pos = atomicAdd(&s_cnt, 1u);
            sk[pos] = key;
        }
    }
    __syncthreads();

    // ---- Phase C: bitonic sort 2048 keys ascending ----
    for (int k = 2; k <= NSEL; k <<= 1) {
        for (int j = k >> 1; j > 0; j >>= 1) {
            int n = tid;
            int i = ((n & ~(j - 1)) << 1) | (n & (j - 1));
            int l = i | j;
            u64 a = sk[i], c = sk[l];
            bool up = ((i & k) == 0);
            if ((a > c) == up) { sk[i] = c; sk[l] = a; }
            __syncthreads();
        }
    }

    // ---- Phase D: gather selected entries ----
    for (int r = tid; r < NSEL; r += 1024) {
        u64 key = sk[r];
        int a = (int)(key & 0xFFFFFFFFu);
        size_t src = (size_t)b * NANCH + a;
        float4 bx = boxes[src];
        int c = cls[src];
        float sc = score[src];
        float off = (float)c * MAXWH;
        float4 sb;
        sb.x = bx.x + off; sb.y = bx.y + off;
        sb.z = bx.z + off; sb.w = bx.w + off;
        float area = (sb.z - sb.x) * (sb.w - sb.y);
        size_t o = (size_t)b * NSEL + r;
        sel_box[o] = bx; sel_sbox[o] = sb; sel_area[o] = area;
        sel_score[o] = sc; sel_cls[o] = c;
    }
}

// ---- Kernel 3: per-class NMS (IoU matrix is block-diagonal by class:
//      cross-class offset boxes are disjoint => iou == 0.0 exactly).
//      One wave per class; no barriers. ----
__global__ __launch_bounds__(1024) void k_cnms(const float4* __restrict__ sel_sbox,
                                               const float* __restrict__ sel_area,
                                               const int* __restrict__ sel_cls,
                                               const float* __restrict__ sel_score,
                                               u64* __restrict__ gkeep) {
    __shared__ u16 wmem[16][NSEL];    // 64 KB: per-wave member list
    __shared__ u64 wkeep[16][NWORD];  // 4 KB: per-wave kept bits (member-position indexed)

    int b = blockIdx.y;
    int cg = blockIdx.x;              // class group 0..4
    int lane = threadIdx.x & 63, wv = threadIdx.x >> 6;
    int c = cg * 16 + wv;             // this wave's class, 0..79
    size_t bb = (size_t)b * NSEL;
    const int* CL = sel_cls + bb;
    const float* SC = sel_score + bb;
    u64 below = (1ULL << lane) - 1ULL;

    // ---- build member list (ascending selected index == descending score) ----
    int n = 0;
    for (int ch = 0; ch < NWORD; ++ch) {
        int i = ch * 64 + lane;
        bool pred = (CL[i] == c) && (SC[i] >= 0.0f);
        u64 bal = __ballot(pred);
        if (pred) wmem[wv][n + __popcll(bal & below)] = (u16)i;
        n += __popcll(bal);
    }

    // ---- greedy NMS over this class's members, 64 at a time ----
    for (int c0 = 0; c0 < n; c0 += 64) {
        int chunkn = n - c0; if (chunkn > 64) chunkn = 64;
        bool mv = lane < chunkn;
        int q = mv ? (int)wmem[wv][c0 + lane] : 0;
        float4 bq = sel_sbox[bb + q];
        float aq = sel_area[bb + q];

        // hit-test vs earlier kept members (only runs when n > 64)
        bool hit = false;
        for (int j = 0; j < c0; ++j) {
            if (!((wkeep[wv][j >> 6] >> (j & 63)) & 1ULL)) continue;
            int p = (int)wmem[wv][j];
            float4 bp = sel_sbox[bb + p];
            float ap = sel_area[bb + p];
            float ltx = fmaxf(bp.x, bq.x), lty = fmaxf(bp.y, bq.y);
            float rbx = fminf(bp.z, bq.z), rby = fminf(bp.w, bq.w);
            float ww = fmaxf(rbx - ltx, 0.0f), hh = fmaxf(rby - lty, 0.0f);
            float inter = ww * hh;
            hit = hit || (mv && (inter / (ap + aq - inter + 1e-16f) > NMS_T));
        }
        u64 avail = __ballot(mv && !hit);

        // build within-chunk adjacency: lane t holds row t
        u64 Rt = 0;
        for (int t = 0; t < chunkn; ++t) {
            int p = (int)wmem[wv][c0 + t];            // LDS broadcast
            float4 bp = sel_sbox[bb + p];             // global broadcast (L1/L2)
            float ap = sel_area[bb + p];
            float ltx = fmaxf(bp.x, bq.x), lty = fmaxf(bp.y, bq.y);
            float rbx = fminf(bp.z, bq.z), rby = fminf(bp.w, bq.w);
            float ww = fmaxf(rbx - ltx, 0.0f), hh = fmaxf(rby - lty, 0.0f);
            float inter = ww * hh;
            u64 row = __ballot(mv && (inter / (ap + aq - inter + 1e-16f) > NMS_T));
            if (lane == t) Rt = row;
        }

        // peel: greedy == lexicographically-first MIS (symmetric adjacency)
        u64 U = avail, kept = 0;
        while (U) {
            bool inU = ((U >> lane) & 1ULL) != 0ULL;
            u64 newk = __ballot(inU && ((Rt & U & below) == 0ULL));
            u64 killed = __ballot((Rt & newk) != 0ULL);
            kept |= newk;
            U &= ~(newk | killed);
        }
        if (lane == 0) wkeep[wv][c0 >> 6] = kept;
        if ((kept >> lane) & 1ULL)
            atomicOr(&gkeep[(size_t)b * NWORD + (q >> 6)], 1ULL << (q & 63));
    }
}

// ---- Kernel 4: compact kept entries (descending-score order) + zero fill ----
__global__ __launch_bounds__(64) void k_out(const u64* __restrict__ gkeep,
                                            const float4* __restrict__ sel_box,
                                            const float* __restrict__ sel_score,
                                            const int* __restrict__ sel_cls,
                                            float* __restrict__ out) {
    int b = blockIdx.x;
    int lane = threadIdx.x;
    const float* SC = sel_score + (size_t)b * NSEL;
    u64 kreg = (lane < NWORD) ? gkeep[(size_t)b * NWORD + lane] : 0ULL;

    int cnt = (lane < NWORD) ? __popcll(kreg) : 0;
    int pre = cnt;
    #pragma unroll
    for (int dd = 1; dd < 64; dd <<= 1) {
        int o = __shfl_up(pre, dd);
        if (lane >= dd) pre += o;
    }
    int total = __shfl(pre, 63);
    int base = pre - cnt;
    float* OUT = out + (size_t)b * MAXDET * 6;
    if (lane < NWORD) {
        u64 m = kreg;
        int rr = 0;
        while (m) {
            int t = __ffsll((long long)m) - 1;
            m &= m - 1;
            int slot = base + rr; ++rr;
            if (slot < MAXDET) {
                int i = lane * 64 + t;
                size_t src = (size_t)b * NSEL + i;
                float4 bx = sel_box[src];
                float sc = SC[i];
                int c = sel_cls[src];
                float* o6 = OUT + slot * 6;
                o6[0] = bx.x; o6[1] = bx.y; o6[2] = bx.z; o6[3] = bx.w;
                o6[4] = sc; o6[5] = (float)c;
            }
        }
    }
    int start = total > MAXDET ? MAXDET : total;
    for (int s = start + lane; s < MAXDET; s += 64) {
        float* o6 = OUT + s * 6;
        o6[0] = 0.0f; o6[1] = 0.0f; o6[2] = 0.0f;
        o6[3] = 0.0f; o6[4] = 0.0f; o6[5] = 0.0f;
    }
}

// ---------------- Launcher ----------------
extern "C" void kernel_launch(void* const* d_in, const int* in_sizes, int n_in,
                              void* d_out, int out_size, void* d_ws, size_t ws_size,
                              hipStream_t stream) {
    const float* pred = (const float*)d_in[0];
    float* out = (float*)d_out;

    char* ws = (char*)d_ws;
    size_t off = 0;
    auto alloc = [&](size_t bytes) -> void* {
        void* p = ws + off;
        off += (bytes + 255) & ~(size_t)255;
        return p;
    };

    u64*    keys      = (u64*)   alloc((size_t)NBATCH * NSORT * 8);
    float4* boxes     = (float4*)alloc((size_t)NBATCH * NANCH * 16);
    int*    cls       = (int*)   alloc((size_t)NBATCH * NANCH * 4);
    float*  score     = (float*) alloc((size_t)NBATCH * NANCH * 4);
    float4* sel_box   = (float4*)alloc((size_t)NBATCH * NSEL * 16);
    float4* sel_sbox  = (float4*)alloc((size_t)NBATCH * NSEL * 16);
    float*  sel_area  = (float*) alloc((size_t)NBATCH * NSEL * 4);
    float*  sel_score = (float*) alloc((size_t)NBATCH * NSEL * 4);
    int*    sel_cls   = (int*)   alloc((size_t)NBATCH * NSEL * 4);
    u64*    gkeep     = (u64*)   alloc((size_t)NBATCH * NWORD * 8);

    dim3 g1((NANCH + 127) / 128, NBATCH);
    k_prep<<<g1, 256, 0, stream>>>(pred, keys, boxes, cls, score);

    k_sel<<<NBATCH, 1024, 0, stream>>>(keys, boxes, cls, score,
                                       sel_box, sel_sbox, sel_area,
                                       sel_score, sel_cls);

    hipMemsetAsync(gkeep, 0, (size_t)NBATCH * NWORD * 8, stream);

    dim3 g3(5, NBATCH);
    k_cnms<<<g3, 1024, 0, stream>>>(sel_sbox, sel_area, sel_cls, sel_score, gkeep);

    k_out<<<NBATCH, 64, 0, stream>>>(gkeep, sel_box, sel_score, sel_cls, out);
}

// Round 11
// 108.992 us; speedup vs baseline: 3.5508x; 1.0302x over previous
//
#include <hip/hip_runtime.h>
#include <hip/hip_bf16.h>
#include <stdint.h>

typedef unsigned long long u64;
typedef unsigned int u32;
typedef unsigned short u16;

#define NANCH 10647
#define NBATCH 16
#define NSORT 16384
#define NSEL 2048
#define NWORD 32
#define NCLS 80
#define CONF_T 0.5f
#define NMS_T 0.5f
#define MAXDET 300
#define MAXWH 4096.0f
#define CANDCAP 10688   // >= NANCH, 64-aligned

// ---------------- Kernel 1: per-anchor prep (+ top-byte histogram) ----------------
__global__ __launch_bounds__(256) void k_prep(const float* __restrict__ pred,
                                              u64* __restrict__ keys,
                                              float4* __restrict__ boxes,
                                              int* __restrict__ cls,
                                              float* __restrict__ score,
                                              u32* __restrict__ ghist) {
    __shared__ float sm[128 * 85];
    __shared__ u32 ph[256];
    int b = blockIdx.y;
    int a0 = blockIdx.x * 128;
    int na = NANCH - a0; if (na > 128) na = 128;
    const float* src = pred + ((size_t)b * NANCH + a0) * 85;
    int tot = na * 85;
    ph[threadIdx.x] = 0;
    for (int i = threadIdx.x; i < tot; i += 256) sm[i] = src[i];
    __syncthreads();
    int t = threadIdx.x;
    u64 kk = 0;
    if (t < na) {
        const float* s = &sm[t * 85];
        float x = s[0], y = s[1], w = s[2], h = s[3], obj = s[4];
        float best = s[5] * obj; int arg = 0;
        #pragma unroll
        for (int c = 1; c < 80; ++c) {
            float v = s[5 + c] * obj;
            if (v > best) { best = v; arg = c; }
        }
        bool valid = obj >= CONF_T;
        float sc = valid ? best : -1.0f;
        int a = a0 + t;
        float4 bx;
        bx.x = x - w * 0.5f; bx.y = y - h * 0.5f;
        bx.z = x + w * 0.5f; bx.w = y + h * 0.5f;
        size_t o = (size_t)b * NANCH + a;
        boxes[o] = bx;
        cls[o] = arg;
        score[o] = sc;
        u32 u = __float_as_uint(sc);
        u32 v = (u & 0x80000000u) ? ~u : (u | 0x80000000u); // ascending map
        u32 hi = ~v;                                        // descending
        kk = ((u64)hi << 32) | (u32)a;
        keys[(size_t)b * NSORT + a] = kk;
    }
    // wave-aggregated 256-bin histogram of key top byte
    u32 bin = (t < na) ? (u32)(kk >> 56) : 0xFFFFFFFFu;
    int lane = t & 63;
    u64 rem = __ballot(t < na);
    while (rem) {
        int srcl = __ffsll((long long)rem) - 1;
        u32 lb = __shfl(bin, srcl);
        u64 same = __ballot(bin == lb) & rem;
        if (lane == srcl) atomicAdd(&ph[lb], (u32)__popcll(same));
        rem &= ~same;
    }
    __syncthreads();
    if (ph[threadIdx.x]) atomicAdd(&ghist[(size_t)b * 256 + threadIdx.x], ph[threadIdx.x]);
}

// ------- Kernel 2: histogram-seeded select + bitonic sort + gather -------
// Invariant through selection: s_cnt + s_rank == NSEL at every loop entry.
__global__ __launch_bounds__(1024) void k_sel(const u64* __restrict__ keys,
                                              const u32* __restrict__ ghist,
                                              const float4* __restrict__ boxes,
                                              const int* __restrict__ cls,
                                              const float* __restrict__ score,
                                              float4* __restrict__ sel_box,
                                              float4* __restrict__ sel_sbox,
                                              float* __restrict__ sel_area,
                                              float* __restrict__ sel_score,
                                              int* __restrict__ sel_cls) {
    __shared__ u64 sk[NSEL];        // 16 KB
    __shared__ u64 cand[CANDCAP];   // 85.5 KB
    __shared__ u32 hist[256];
    __shared__ u32 hsc[256];
    __shared__ u64 s_red[16];
    __shared__ u32 s_D0, s_D, s_rank, s_cnt, s_cand;

    int b = blockIdx.x;
    int tid = threadIdx.x;
    int lane = tid & 63;
    u64 below = (1ULL << lane) - 1ULL;
    const u64* KB = keys + (size_t)b * NSORT;

    if (tid == 0) { s_cnt = 0; s_cand = 0; }
    for (int i = tid; i < NSEL; i += 1024) sk[i] = ~0ULL;   // safety fill
    // ---- round 0: digit from precomputed histogram ----
    if (tid < 256) hist[tid] = ghist[(size_t)b * 256 + tid];
    __syncthreads();
    if (tid < 64) {
        u32 h0 = hist[tid*4], h1 = hist[tid*4+1], h2 = hist[tid*4+2], h3 = hist[tid*4+3];
        u32 loc = h0 + h1 + h2 + h3;
        u32 p = loc;
        #pragma unroll
        for (int o = 1; o < 64; o <<= 1) { u32 t2 = __shfl_up(p, o); if (lane >= o) p += t2; }
        u32 base = p - loc;
        hsc[tid*4]   = base + h0;
        hsc[tid*4+1] = base + h0 + h1;
        hsc[tid*4+2] = base + h0 + h1 + h2;
        hsc[tid*4+3] = base + h0 + h1 + h2 + h3;
    }
    __syncthreads();
    if (tid < 256) {
        u32 inc = hsc[tid], cb = inc - hist[tid];
        if (cb < NSEL && NSEL <= inc) { s_D0 = tid; s_rank = NSEL - cb; }
    }
    __syncthreads();
    u32 D0 = s_D0;

    // ---- single fused scan: sure-set -> sk, boundary bucket -> cand ----
    for (int it = 0; it < 11; ++it) {
        int i = tid + it * 1024;
        bool inb = i < NANCH;
        u64 kk = inb ? KB[i] : 0ULL;
        u32 top = (u32)(kk >> 56);
        bool is_s = inb && (top < D0);
        bool is_c = inb && (top == D0);
        u64 bs = __ballot(is_s), bc = __ballot(is_c);
        u32 base_s = 0, base_c = 0;
        if (lane == 0) {
            if (bs) base_s = atomicAdd(&s_cnt, (u32)__popcll(bs));
            if (bc) base_c = atomicAdd(&s_cand, (u32)__popcll(bc));
        }
        base_s = __shfl(base_s, 0); base_c = __shfl(base_c, 0);
        if (is_s) sk[base_s + __popcll(bs & below)] = kk;
        if (is_c) cand[base_c + __popcll(bc & below)] = kk;
    }
    __syncthreads();

    // ---- refine within cand; append sure-members to sk each round ----
    const int shifts2[5] = {48, 40, 32, 8, 0};
    for (int rr = 0; ; ++rr) {
        u32 cn = s_cand, r = s_rank;
        if (r == cn || rr == 5) {
            // all remaining cand are selected (r == cn), or terminal safety
            for (u32 i0 = 0; i0 < cn; i0 += 1024) {
                u32 i = i0 + tid;
                bool take = i < cn;
                u64 kk = take ? cand[i] : 0ULL;
                u64 bt = __ballot(take);
                u32 base = 0;
                if (lane == 0 && bt) base = atomicAdd(&s_cnt, (u32)__popcll(bt));
                base = __shfl(base, 0);
                if (take) sk[base + __popcll(bt & below)] = kk;
            }
            break;
        }
        if (r == 1) {
            // only the minimum of cand is selected
            u64 best = ~0ULL;
            for (u32 i = tid; i < cn; i += 1024) { u64 kk = cand[i]; if (kk < best) best = kk; }
            #pragma unroll
            for (int o = 32; o > 0; o >>= 1) {
                u64 other = __shfl_down(best, o);
                if (other < best) best = other;
            }
            if (lane == 0) s_red[tid >> 6] = best;
            __syncthreads();
            if (tid == 0) {
                u64 m = s_red[0];
                for (int w2 = 1; w2 < 16; ++w2) if (s_red[w2] < m) m = s_red[w2];
                sk[atomicAdd(&s_cnt, 1u)] = m;
            }
            break;
        }
        int shift = shifts2[rr];
        if (tid < 256) hist[tid] = 0;
        __syncthreads();
        for (u32 i = tid; i < cn; i += 1024)
            atomicAdd(&hist[(u32)(cand[i] >> shift) & 0xFFu], 1u);
        __syncthreads();
        if (tid < 64) {
            u32 h0 = hist[tid*4], h1 = hist[tid*4+1], h2 = hist[tid*4+2], h3 = hist[tid*4+3];
            u32 loc = h0 + h1 + h2 + h3;
            u32 p = loc;
            #pragma unroll
            for (int o = 1; o < 64; o <<= 1) { u32 t2 = __shfl_up(p, o); if (lane >= o) p += t2; }
            u32 base = p - loc;
            hsc[tid*4]   = base + h0;
            hsc[tid*4+1] = base + h0 + h1;
            hsc[tid*4+2] = base + h0 + h1 + h2;
            hsc[tid*4+3] = base + h0 + h1 + h2 + h3;
        }
        __syncthreads();
        if (tid < 256) {
            u32 inc = hsc[tid], cb = inc - hist[tid];
            if (cb < r && r <= inc) { s_D = tid; s_rank = r - cb; }
        }
        __syncthreads();
        u32 D = s_D;
        // partition: digit<D -> sk (sure members), digit==D -> cand, else drop
        u64 mk[11], mc[11]; int nk = 0, nc = 0;
        for (u32 i = tid; i < cn; i += 1024) {
            u64 kk = cand[i];
            u32 dg = (u32)(kk >> shift) & 0xFFu;
            if (dg < D) mk[nk++] = kk;
            else if (dg == D) mc[nc++] = kk;
        }
        __syncthreads();
        if (tid == 0) s_cand = 0;
        __syncthreads();
        if (nk) { u32 p = atomicAdd(&s_cnt, (u32)nk); for (int j = 0; j < nk; ++j) sk[p + j] = mk[j]; }
        if (nc) { u32 p = atomicAdd(&s_cand, (u32)nc); for (int j = 0; j < nc; ++j) cand[p + j] = mc[j]; }
        __syncthreads();
    }
    __syncthreads();

    // ---- bitonic sort 2048 keys ascending ----
    for (int k = 2; k <= NSEL; k <<= 1) {
        for (int j = k >> 1; j > 0; j >>= 1) {
            int n = tid;
            int i = ((n & ~(j - 1)) << 1) | (n & (j - 1));
            int l = i | j;
            u64 a = sk[i], c = sk[l];
            bool up = ((i & k) == 0);
            if ((a > c) == up) { sk[i] = c; sk[l] = a; }
            __syncthreads();
        }
    }

    // ---- gather selected entries (clamped index: fault-safe) ----
    for (int r2 = tid; r2 < NSEL; r2 += 1024) {
        u64 key = sk[r2];
        int a = (int)(key & 0xFFFFFFFFu);
        if ((unsigned)a >= NANCH) a = 0;   // should never trigger
        size_t src = (size_t)b * NANCH + a;
        float4 bx = boxes[src];
        int c = cls[src];
        float sc = score[src];
        float off = (float)c * MAXWH;
        float4 sb;
        sb.x = bx.x + off; sb.y = bx.y + off;
        sb.z = bx.z + off; sb.w = bx.w + off;
        float area = (sb.z - sb.x) * (sb.w - sb.y);
        size_t o = (size_t)b * NSEL + r2;
        sel_box[o] = bx; sel_sbox[o] = sb; sel_area[o] = area;
        sel_score[o] = sc; sel_cls[o] = c;
    }
}

// ---- Kernel 3: per-class NMS (IoU matrix is block-diagonal by class) ----
__global__ __launch_bounds__(1024) void k_cnms(const float4* __restrict__ sel_sbox,
                                               const float* __restrict__ sel_area,
                                               const int* __restrict__ sel_cls,
                                               const float* __restrict__ sel_score,
                                               u64* __restrict__ gkeep) {
    __shared__ u16 wmem[16][NSEL];    // 64 KB: per-wave member list
    __shared__ u64 wkeep[16][NWORD];  // 4 KB: per-wave kept bits

    int b = blockIdx.y;
    int cg = blockIdx.x;              // class group 0..4
    int lane = threadIdx.x & 63, wv = threadIdx.x >> 6;
    int c = cg * 16 + wv;             // this wave's class, 0..79
    size_t bb = (size_t)b * NSEL;
    const int* CL = sel_cls + bb;
    const float* SC = sel_score + bb;
    u64 below = (1ULL << lane) - 1ULL;

    // ---- build member list (ascending selected index == descending score) ----
    int n = 0;
    for (int ch = 0; ch < NWORD; ++ch) {
        int i = ch * 64 + lane;
        bool pred = (CL[i] == c) && (SC[i] >= 0.0f);
        u64 bal = __ballot(pred);
        if (pred) wmem[wv][n + __popcll(bal & below)] = (u16)i;
        n += __popcll(bal);
    }

    // ---- greedy NMS over this class's members, 64 at a time ----
    for (int c0 = 0; c0 < n; c0 += 64) {
        int chunkn = n - c0; if (chunkn > 64) chunkn = 64;
        bool mv = lane < chunkn;
        int q = mv ? (int)wmem[wv][c0 + lane] : 0;
        float4 bq = sel_sbox[bb + q];
        float aq = sel_area[bb + q];

        // hit-test vs earlier kept members (only runs when n > 64)
        bool hit = false;
        for (int j = 0; j < c0; ++j) {
            if (!((wkeep[wv][j >> 6] >> (j & 63)) & 1ULL)) continue;
            int p = (int)wmem[wv][j];
            float4 bp = sel_sbox[bb + p];
            float ap = sel_area[bb + p];
            float ltx = fmaxf(bp.x, bq.x), lty = fmaxf(bp.y, bq.y);
            float rbx = fminf(bp.z, bq.z), rby = fminf(bp.w, bq.w);
            float ww = fmaxf(rbx - ltx, 0.0f), hh = fmaxf(rby - lty, 0.0f);
            float inter = ww * hh;
            hit = hit || (mv && (inter / (ap + aq - inter + 1e-16f) > NMS_T));
        }
        u64 avail = __ballot(mv && !hit);

        // build within-chunk adjacency: lane t holds row t
        u64 Rt = 0;
        for (int t = 0; t < chunkn; ++t) {
            int p = (int)wmem[wv][c0 + t];            // LDS broadcast
            float4 bp = sel_sbox[bb + p];             // global broadcast (L1/L2)
            float ap = sel_area[bb + p];
            float ltx = fmaxf(bp.x, bq.x), lty = fmaxf(bp.y, bq.y);
            float rbx = fminf(bp.z, bq.z), rby = fminf(bp.w, bq.w);
            float ww = fmaxf(rbx - ltx, 0.0f), hh = fmaxf(rby - lty, 0.0f);
            float inter = ww * hh;
            u64 row = __ballot(mv && (inter / (ap + aq - inter + 1e-16f) > NMS_T));
            if (lane == t) Rt = row;
        }

        // peel: greedy == lexicographically-first MIS (symmetric adjacency)
        u64 U = avail, kept = 0;
        while (U) {
            bool inU = ((U >> lane) & 1ULL) != 0ULL;
            u64 newk = __ballot(inU && ((Rt & U & below) == 0ULL));
            u64 killed = __ballot((Rt & newk) != 0ULL);
            kept |= newk;
            U &= ~(newk | killed);
        }
        if (lane == 0) wkeep[wv][c0 >> 6] = kept;
        if ((kept >> lane) & 1ULL)
            atomicOr(&gkeep[(size_t)b * NWORD + (q >> 6)], 1ULL << (q & 63));
    }
}

// ---- Kernel 4: compact kept entries (descending-score order) + zero fill ----
__global__ __launch_bounds__(64) void k_out(const u64* __restrict__ gkeep,
                                            const float4* __restrict__ sel_box,
                                            const float* __restrict__ sel_score,
                                            const int* __restrict__ sel_cls,
                                            float* __restrict__ out) {
    int b = blockIdx.x;
    int lane = threadIdx.x;
    const float* SC = sel_score + (size_t)b * NSEL;
    u64 kreg = (lane < NWORD) ? gkeep[(size_t)b * NWORD + lane] : 0ULL;

    int cnt = (lane < NWORD) ? __popcll(kreg) : 0;
    int pre = cnt;
    #pragma unroll
    for (int dd = 1; dd < 64; dd <<= 1) {
        int o = __shfl_up(pre, dd);
        if (lane >= dd) pre += o;
    }
    int total = __shfl(pre, 63);
    int base = pre - cnt;
    float* OUT = out + (size_t)b * MAXDET * 6;
    if (lane < NWORD) {
        u64 m = kreg;
        int rr = 0;
        while (m) {
            int t = __ffsll((long long)m) - 1;
            m &= m - 1;
            int slot = base + rr; ++rr;
            if (slot < MAXDET) {
                int i = lane * 64 + t;
                size_t src = (size_t)b * NSEL + i;
                float4 bx = sel_box[src];
                float sc = SC[i];
                int c = sel_cls[src];
                float* o6 = OUT + slot * 6;
                o6[0] = bx.x; o6[1] = bx.y; o6[2] = bx.z; o6[3] = bx.w;
                o6[4] = sc; o6[5] = (float)c;
            }
        }
    }
    int start = total > MAXDET ? MAXDET : total;
    for (int s = start + lane; s < MAXDET; s += 64) {
        float* o6 = OUT + s * 6;
        o6[0] = 0.0f; o6[1] = 0.0f; o6[2] = 0.0f;
        o6[3] = 0.0f; o6[4] = 0.0f; o6[5] = 0.0f;
    }
}

// ---------------- Launcher ----------------
extern "C" void kernel_launch(void* const* d_in, const int* in_sizes, int n_in,
                              void* d_out, int out_size, void* d_ws, size_t ws_size,
                              hipStream_t stream) {
    const float* pred = (const float*)d_in[0];
    float* out = (float*)d_out;

    char* ws = (char*)d_ws;
    size_t off = 0;
    auto alloc = [&](size_t bytes) -> void* {
        void* p = ws + off;
        off += (bytes + 255) & ~(size_t)255;
        return p;
    };

    u64*    keys      = (u64*)   alloc((size_t)NBATCH * NSORT * 8);
    float4* boxes     = (float4*)alloc((size_t)NBATCH * NANCH * 16);
    int*    cls       = (int*)   alloc((size_t)NBATCH * NANCH * 4);
    float*  score     = (float*) alloc((size_t)NBATCH * NANCH * 4);
    float4* sel_box   = (float4*)alloc((size_t)NBATCH * NSEL * 16);
    float4* sel_sbox  = (float4*)alloc((size_t)NBATCH * NSEL * 16);
    float*  sel_area  = (float*) alloc((size_t)NBATCH * NSEL * 4);
    float*  sel_score = (float*) alloc((size_t)NBATCH * NSEL * 4);
    int*    sel_cls   = (int*)   alloc((size_t)NBATCH * NSEL * 4);
    u64*    gkeep     = (u64*)   alloc((size_t)NBATCH * NWORD * 8);       // 4 KB
    u32*    ghist     = (u32*)   alloc((size_t)NBATCH * 256 * 4);         // 16 KB (contiguous after gkeep)

    // zero gkeep + ghist in one async memset (contiguous, 256-aligned)
    hipMemsetAsync(gkeep, 0, (size_t)NBATCH * NWORD * 8 + (size_t)NBATCH * 256 * 4, stream);

    dim3 g1((NANCH + 127) / 128, NBATCH);
    k_prep<<<g1, 256, 0, stream>>>(pred, keys, boxes, cls, score, ghist);

    k_sel<<<NBATCH, 1024, 0, stream>>>(keys, ghist, boxes, cls, score,
                                       sel_box, sel_sbox, sel_area,
                                       sel_score, sel_cls);

    dim3 g3(5, NBATCH);
    k_cnms<<<g3, 1024, 0, stream>>>(sel_sbox, sel_area, sel_cls, sel_score, gkeep);

    k_out<<<NBATCH, 64, 0, stream>>>(gkeep, sel_box, sel_score, sel_cls, out);
}